// Round 1
// baseline (8636.963 us; speedup 1.0000x reference)
//
#include <hip/hip_runtime.h>

// RNN_34505767256242: emb lookup -> LSTM(B=16,S=512,E=128,H=256) -> vocab proj (V=32000)
//
// v2 plan (fused input GEMM):
//  prep : convert w_ih, w_out f32 -> bf16; gather emb[x] -> xe bf16 in MFMA A-frag layout
//  lstm : single WG, 16 waves; w_hh AND w_ih register-resident as MFMA B-frags;
//         gates = bias + xe@w_ih^T + h@w_hh^T (all MFMA, f32 accum);
//         h double-buffered in LDS (1 barrier/step); hs stores deferred past barrier.
//         Per-step global traffic: 4KB xe (L1-broadcast across waves) + 8KB hs write,
//         vs 64KB f32 xg stream in v1 (which was 19k of the 20k cyc/step).
//  gemm<PERMUTE> : logits = hs @ w_out^T + b_out, with XCD-aware block swizzle.

typedef __bf16 v8bf __attribute__((ext_vector_type(8)));
typedef __bf16 v4bf __attribute__((ext_vector_type(4)));
typedef float  v4f  __attribute__((ext_vector_type(4)));

#define BATCH 16
#define SEQ   512
#define EMB   128
#define HID   256
#define G4H   1024
#define VOCAB 32000
#define MROWS (BATCH*SEQ)   // 8192

__device__ __forceinline__ float fast_sigmoid(float x) {
    float e = __builtin_amdgcn_exp2f(-1.442695040888963f * x);
    return __builtin_amdgcn_rcpf(1.0f + e);
}
__device__ __forceinline__ float fast_tanh(float x) {
    float e = __builtin_amdgcn_exp2f(-2.885390081777927f * x);
    return 2.0f * __builtin_amdgcn_rcpf(1.0f + e) - 1.0f;
}

// ---------------- f32 -> bf16 convert (vectorized x4) ----------------
__global__ void cvt_kernel(const float* __restrict__ in, __bf16* __restrict__ out, int n4) {
    int i = blockIdx.x * blockDim.x + threadIdx.x;
    if (i < n4) {
        float4 v = ((const float4*)in)[i];
        v4bf p;
        p[0] = (__bf16)v.x; p[1] = (__bf16)v.y; p[2] = (__bf16)v.z; p[3] = (__bf16)v.w;
        ((v4bf*)out)[i] = p;
    }
}

// ---------------- gather emb[x] -> bf16, MFMA A-frag layout ----------------
// Consumer (lstm): frag s, lane l reads xe[t*2048 + s*512 + l*8 + j]
//                  == emb_row[b = l&15][k = s*32 + (l>>4)*8 + j]
// Producer: thread (b = tid>>4, kk = tid&15) covers k = kk*8..kk*8+7:
//           s = kk>>2, quad = kk&3, dst = t*2048 + s*512 + (quad*16 + b)*8
__global__ __launch_bounds__(256)
void xe_prep_kernel(const int* __restrict__ x, const float* __restrict__ emb,
                    __bf16* __restrict__ xe)
{
    int t   = blockIdx.x;
    int tid = threadIdx.x;
    int b = tid >> 4, kk = tid & 15;
    int idx = x[b * SEQ + t];
    const float* src = emb + (size_t)idx * EMB + kk * 8;
    float4 v0 = *(const float4*)src;
    float4 v1 = *(const float4*)(src + 4);
    v8bf p;
    p[0] = (__bf16)v0.x; p[1] = (__bf16)v0.y; p[2] = (__bf16)v0.z; p[3] = (__bf16)v0.w;
    p[4] = (__bf16)v1.x; p[5] = (__bf16)v1.y; p[6] = (__bf16)v1.z; p[7] = (__bf16)v1.w;
    int s = kk >> 2, quad = kk & 3;
    *(v8bf*)&xe[(size_t)t * 2048 + s * 512 + (quad * 16 + b) * 8] = p;
}

// ---------------- generic 128x128 MFMA GEMM:  C = A * B^T + bias ----------------
template<bool GATHER, bool PERMUTE>
__global__ __launch_bounds__(256)
void gemm_kernel(const __bf16* __restrict__ A, const __bf16* __restrict__ B,
                 const float* __restrict__ bias1, const float* __restrict__ bias2,
                 float* __restrict__ out, int K, int ldout,
                 const int* __restrict__ xidx, const float* __restrict__ emb)
{
    __shared__ __bf16 Al[128 * 40];
    __shared__ __bf16 Bl[128 * 40];

    const int tid  = threadIdx.x;
    const int w    = tid >> 6, l = tid & 63;
    const int m    = l & 15, quad = l >> 4;
    const int wm   = w >> 1, wn = w & 1;

    // XCD-aware bijective block swizzle (requires nwg % 8 == 0; vocab gemm: 250*64=16000)
    int bxi = blockIdx.x, byi = blockIdx.y;
    {
        int nwg = gridDim.x * gridDim.y;
        if ((nwg & 7) == 0) {
            int wg  = byi * gridDim.x + bxi;
            int cpx = nwg >> 3;
            int swz = (wg & 7) * cpx + (wg >> 3);
            bxi = swz % gridDim.x;
            byi = swz / gridDim.x;
        }
    }
    const int row0 = byi * 128;
    const int col0 = bxi * 128;

    v4f acc[4][4];
    #pragma unroll
    for (int i = 0; i < 4; ++i)
        #pragma unroll
        for (int j = 0; j < 4; ++j) {
            v4f z = {0.f, 0.f, 0.f, 0.f};
            acc[i][j] = z;
        }

    for (int k0 = 0; k0 < K; k0 += 32) {
        if (GATHER) {
            #pragma unroll
            for (int it = 0; it < 4; ++it) {
                int e = it * 256 + tid;
                int r = e >> 3, sg = e & 7;
                int mr = row0 + r;
                int idx = xidx[(mr & 15) * SEQ + (mr >> 4)];
                float4 v = *(const float4*)(emb + (size_t)idx * EMB + k0 + sg * 4);
                v4bf p;
                p[0] = (__bf16)v.x; p[1] = (__bf16)v.y; p[2] = (__bf16)v.z; p[3] = (__bf16)v.w;
                *(v4bf*)&Al[r * 40 + sg * 4] = p;
            }
        } else {
            #pragma unroll
            for (int it = 0; it < 2; ++it) {
                int e = it * 256 + tid;
                int r = e >> 2, sg = e & 3;
                int4 v = *(const int4*)(A + (size_t)(row0 + r) * K + k0 + sg * 8);
                *(int4*)&Al[r * 40 + sg * 8] = v;
            }
        }
        #pragma unroll
        for (int it = 0; it < 2; ++it) {
            int e = it * 256 + tid;
            int r = e >> 2, sg = e & 3;
            int4 v = *(const int4*)(B + (size_t)(col0 + r) * K + k0 + sg * 8);
            *(int4*)&Bl[r * 40 + sg * 8] = v;
        }
        __syncthreads();

        v8bf af[4], bfr[4];
        #pragma unroll
        for (int i = 0; i < 4; ++i)
            af[i] = *(const v8bf*)&Al[(wm * 64 + i * 16 + m) * 40 + quad * 8];
        #pragma unroll
        for (int j = 0; j < 4; ++j)
            bfr[j] = *(const v8bf*)&Bl[(wn * 64 + j * 16 + m) * 40 + quad * 8];

        #pragma unroll
        for (int i = 0; i < 4; ++i)
            #pragma unroll
            for (int j = 0; j < 4; ++j)
                acc[i][j] = __builtin_amdgcn_mfma_f32_16x16x32_bf16(af[i], bfr[j], acc[i][j], 0, 0, 0);
        __syncthreads();
    }

    #pragma unroll
    for (int j = 0; j < 4; ++j) {
        int colg = col0 + wn * 64 + j * 16 + m;
        float bs = bias1[colg];
        if (bias2) bs += bias2[colg];
        #pragma unroll
        for (int i = 0; i < 4; ++i) {
            #pragma unroll
            for (int r = 0; r < 4; ++r) {
                int rg = row0 + wm * 64 + i * 16 + quad * 4 + r;
                size_t orow = PERMUTE ? (size_t)((rg & 15) * SEQ + (rg >> 4)) : (size_t)rg;
                out[orow * (size_t)ldout + colg] = acc[i][j][r] + bs;
            }
        }
    }
}

// ---------------- LSTM recurrence: single WG, 16 waves, both weights in registers ----------------
// xe:  [SEQ][2048] bf16, A-frag layout (4KB/step)
// wih: [4H][E] bf16 (pre-converted); w_hh: [4H][H] f32
// hs out: bf16 [SEQ*BATCH][H], row = t*16 + b
__global__ __launch_bounds__(1024)
void lstm_kernel(const __bf16* __restrict__ xe, const __bf16* __restrict__ wih,
                 const float* __restrict__ w_hh, const float* __restrict__ b_ih,
                 const float* __restrict__ b_hh, __bf16* __restrict__ hs)
{
    // h double-buffered in A-frag layout: elem (k>>3)*128 + b*8 + (k&7)
    __shared__ __align__(16) __bf16 h_lds[2][4096];

    const int tid  = threadIdx.x;
    const int w    = tid >> 6;      // wave 0..15 -> owns gate cols q*256 + [16w, 16w+16)
    const int l    = tid & 63;
    const int m    = l & 15;
    const int quad = l >> 4;

    // ---- w_hh B-frags: bw[q][s] = W_hh[q*256 + 16w + m][s*32 + quad*8 + j] ----
    v8bf bw[4][8];
    #pragma unroll
    for (int q = 0; q < 4; ++q)
        #pragma unroll
        for (int s = 0; s < 8; ++s) {
            const float* src = w_hh + (size_t)(q * 256 + w * 16 + m) * HID + s * 32 + quad * 8;
            float4 v0 = *(const float4*)(src);
            float4 v1 = *(const float4*)(src + 4);
            v8bf f;
            f[0] = (__bf16)v0.x; f[1] = (__bf16)v0.y; f[2] = (__bf16)v0.z; f[3] = (__bf16)v0.w;
            f[4] = (__bf16)v1.x; f[5] = (__bf16)v1.y; f[6] = (__bf16)v1.z; f[7] = (__bf16)v1.w;
            bw[q][s] = f;
        }

    // ---- w_ih B-frags (bf16 direct): bx[q][s] = W_ih[q*256 + 16w + m][s*32 + quad*8 + j] ----
    v8bf bx[4][4];
    #pragma unroll
    for (int q = 0; q < 4; ++q)
        #pragma unroll
        for (int s = 0; s < 4; ++s)
            bx[q][s] = *(const v8bf*)&wih[(size_t)(q * 256 + w * 16 + m) * EMB + s * 32 + quad * 8];

    // per-thread gate biases (col = q*256 + 16w + m)
    float bs4[4];
    #pragma unroll
    for (int q = 0; q < 4; ++q) {
        int col = q * 256 + w * 16 + m;
        bs4[q] = b_ih[col] + b_hh[col];
    }

    for (int i = tid; i < 4096; i += 1024) h_lds[0][i] = (__bf16)0.0f;

    float c0[4] = {0.f, 0.f, 0.f, 0.f};   // c[b = quad*4+r][hid = 16w+m]

    __syncthreads();

    const int k      = w * 16 + m;
    const int hw_off = (k >> 3) * 128 + (k & 7);

    for (int t = 0; t < SEQ; ++t) {
        // xe A-frags for this step (global, L1-broadcast across the 16 waves; issued early)
        const __bf16* xet = xe + (size_t)t * 2048;
        v8bf xf[4];
        #pragma unroll
        for (int s = 0; s < 4; ++s)
            xf[s] = *(const v8bf*)&xet[s * 512 + l * 8];

        const __bf16* hb = h_lds[t & 1];

        v4f accq[4];
        #pragma unroll
        for (int q = 0; q < 4; ++q) {
            v4f a;
            a[0] = bs4[q]; a[1] = bs4[q]; a[2] = bs4[q]; a[3] = bs4[q];
            accq[q] = a;
        }

        // h part first (LDS, fast) — xe loads fly in parallel
        #pragma unroll
        for (int s = 0; s < 8; ++s) {
            v8bf af = *(const v8bf*)&hb[s * 512 + l * 8];
            #pragma unroll
            for (int q = 0; q < 4; ++q)
                accq[q] = __builtin_amdgcn_mfma_f32_16x16x32_bf16(af, bw[q][s], accq[q], 0, 0, 0);
        }
        // x part
        #pragma unroll
        for (int s = 0; s < 4; ++s)
            #pragma unroll
            for (int q = 0; q < 4; ++q)
                accq[q] = __builtin_amdgcn_mfma_f32_16x16x32_bf16(xf[s], bx[q][s], accq[q], 0, 0, 0);

        // nonlinearities + state update; write new h to the OTHER LDS buffer
        __bf16* hwv = h_lds[(t + 1) & 1];
        __bf16 hreg[4];
        #pragma unroll
        for (int r = 0; r < 4; ++r) {
            float i_ = fast_sigmoid(accq[0][r]);
            float f_ = fast_sigmoid(accq[1][r]);
            float g_ = fast_tanh(accq[2][r]);
            float o_ = fast_sigmoid(accq[3][r]);
            float c  = f_ * c0[r] + i_ * g_;
            c0[r] = c;
            float h = o_ * fast_tanh(c);
            __bf16 hv = (__bf16)h;
            hreg[r] = hv;
            hwv[hw_off + (quad * 4 + r) * 8] = hv;
        }
        __syncthreads();   // new h visible; reads of old buffer complete

        // deferred global hs stores: vmcnt drain lands at NEXT step's barrier (~full step of latency hiding)
        #pragma unroll
        for (int r = 0; r < 4; ++r)
            hs[(size_t)(t * 16 + quad * 4 + r) * HID + k] = hreg[r];
    }
}

extern "C" void kernel_launch(void* const* d_in, const int* in_sizes, int n_in,
                              void* d_out, int out_size, void* d_ws, size_t ws_size,
                              hipStream_t stream) {
    const int*   x     = (const int*)d_in[0];      // [B,S] int32
    const float* emb   = (const float*)d_in[1];    // [VOCAB, EMB]
    const float* w_ih  = (const float*)d_in[2];    // [4H, EMB]
    const float* w_hh  = (const float*)d_in[3];    // [4H, H]
    const float* b_ih  = (const float*)d_in[4];    // [4H]
    const float* b_hh  = (const float*)d_in[5];    // [4H]
    const float* w_out = (const float*)d_in[6];    // [VOCAB, H]
    const float* b_out = (const float*)d_in[7];    // [VOCAB]
    float* out = (float*)d_out;

    char* ws = (char*)d_ws;
    __bf16* xebuf = (__bf16*)(ws);                 // 512*2048*2  =  2,097,152 B
    __bf16* hsbuf = (__bf16*)(ws + 2097152);       // 8192*256*2  =  4,194,304 B
    __bf16* wihb  = (__bf16*)(ws + 6291456);       // 1024*128*2  =    262,144 B
    __bf16* woutb = (__bf16*)(ws + 6553600);       // 32000*256*2 = 16,384,000 B

    // prep: weight conversions + embedded-token gather (replaces the whole phase-1 GEMM)
    cvt_kernel<<<(G4H * EMB / 4 + 255) / 256, 256, 0, stream>>>(w_ih, wihb, G4H * EMB / 4);
    cvt_kernel<<<(VOCAB * HID / 4 + 255) / 256, 256, 0, stream>>>(w_out, woutb, VOCAB * HID / 4);
    xe_prep_kernel<<<SEQ, 256, 0, stream>>>(x, emb, xebuf);

    // fused LSTM (single WG): gates = bias + xe@w_ih^T + h@w_hh^T
    lstm_kernel<<<1, 1024, 0, stream>>>(xebuf, wihb, w_hh, b_ih, b_hh, hsbuf);

    // vocab projection: logits = hs @ w_out^T + b_out  -> out[b][t][v]
    gemm_kernel<false, true><<<dim3(VOCAB / 128, MROWS / 128), 256, 0, stream>>>(
        hsbuf, woutb, b_out, nullptr, out, HID, VOCAB, nullptr, nullptr);
}